// Round 5
// baseline (322.421 us; speedup 1.0000x reference)
//
#include <hip/hip_runtime.h>
#include <hip/hip_bf16.h>
#include <math.h>

#define B_SEG 64
#define HDIM 256
#define HDIV 128
#define NHEADS 4
#define DH 32
#define VSTR 520   // V^T row stride (pad 512+8)
#define PSTR 136   // P row stride (pad 128+8)

typedef unsigned short u16;
typedef unsigned int u32;

typedef __attribute__((ext_vector_type(8))) short s8v;   // 8 x bf16
typedef __attribute__((ext_vector_type(4))) float f4v;   // mfma accum

__device__ __forceinline__ u16 f2bf(float f) {
    u32 v;
    __builtin_memcpy(&v, &f, 4);
    u32 r = v + 0x7fffu + ((v >> 16) & 1u);
    return (u16)(r >> 16);
}

// Weight prep (f32->bf16, head-deinterleave c=d*4+h -> c'=h*32+d, BN fold)
// + block 1092 computes ragged offsets into meta.
// meta: [0..63] src counts, [64..127] dst counts, [128..191] src offs, [192..255] dst offs
__global__ __launch_bounds__(256) void k_prep(
    const float* __restrict__ Wq, const float* __restrict__ bq,
    const float* __restrict__ Wk, const float* __restrict__ bk,
    const float* __restrict__ Wv, const float* __restrict__ bv,
    const float* __restrict__ Wm, const float* __restrict__ bm,
    const float* __restrict__ W1, const float* __restrict__ b1,
    const float* __restrict__ g1, const float* __restrict__ be1,
    const float* __restrict__ rm1, const float* __restrict__ rv1,
    const float* __restrict__ W2, const float* __restrict__ b2,
    const float* __restrict__ g2, const float* __restrict__ be2,
    const float* __restrict__ rm2, const float* __restrict__ rv2,
    const int* __restrict__ sc_raw, const int* __restrict__ dc_raw,
    int* __restrict__ meta,
    u16* __restrict__ pWq, u16* __restrict__ pWkv, u16* __restrict__ pWm,
    u16* __restrict__ pW1, u16* __restrict__ pW2,
    float* __restrict__ bqp, float* __restrict__ bkvp, float* __restrict__ bmp,
    float* __restrict__ sc1, float* __restrict__ sh1,
    float* __restrict__ sc2, float* __restrict__ sh2) {
    if (blockIdx.x == 1092) {
        if (threadIdx.x == 0) {
            bool is64 = (sc_raw[1] == 0);  // counts in [256,512]
            int so = 0, dofs = 0;
            for (int i = 0; i < B_SEG; i++) {
                int s = is64 ? sc_raw[2 * i] : sc_raw[i];
                int d = is64 ? dc_raw[2 * i] : dc_raw[i];
                meta[i] = s; meta[64 + i] = d;
                meta[128 + i] = so; meta[192 + i] = dofs;
                so += s; dofs += d;
            }
        }
        return;
    }
    int idx = blockIdx.x * 256 + threadIdx.x;
    if (idx < 32768) {                       // Wq': rows permuted
        int cp = idx >> 8, k = idx & 255;
        int c = ((cp & 31) << 2) | (cp >> 5);
        pWq[idx] = f2bf(Wq[c * 256 + k]);
    } else if (idx < 98304) {                // Wkv': k rows 0..127, v rows 128..255
        int i = idx - 32768;
        int rp = i >> 8, k = i & 255;
        int r = rp & 127;
        int c = ((r & 31) << 2) | (r >> 5);
        float v = (rp < 128) ? Wk[c * 256 + k] : Wv[c * 256 + k];
        pWkv[i] = f2bf(v);
    } else if (idx < 114688) {               // Wm': cols permuted
        int i = idx - 98304;
        int o = i >> 7, cp = i & 127;
        int c = ((cp & 31) << 2) | (cp >> 5);
        pWm[i] = f2bf(Wm[o * 128 + c]);
    } else if (idx < 212992) {               // W1 plain
        int i = idx - 114688;
        pW1[i] = f2bf(W1[i]);
    } else if (idx < 278528) {               // W2 plain
        int i = idx - 212992;
        pW2[i] = f2bf(W2[i]);
    } else if (idx < 279552) {               // params
        int p = idx - 278528;
        if (p < 128) { int c = ((p & 31) << 2) | (p >> 5); bqp[p] = bq[c]; }
        else if (p < 384) {
            int r = p - 128; int rr = r & 127;
            int c = ((rr & 31) << 2) | (rr >> 5);
            bkvp[r] = (r < 128) ? bk[c] : bv[c];
        } else if (p < 512) { bmp[p - 384] = bm[p - 384]; }
        else if (p < 768) {
            int o = p - 512; float s = g1[o] * rsqrtf(rv1[o] + 1e-5f);
            sc1[o] = s; sh1[o] = (b1[o] - rm1[o]) * s + be1[o];
        } else {
            int o = p - 768; float s = g2[o] * rsqrtf(rv2[o] + 1e-5f);
            sc2[o] = s; sh2[o] = (b2[o] - rm2[o]) * s + be2[o];
        }
    }
}

// f32 -> bf16 contiguous convert. y==0: src_h -> srcb; y==1: dst_h -> dstb.
__global__ __launch_bounds__(256) void k_convert(
    const float* __restrict__ src, const float* __restrict__ dst,
    u16* __restrict__ srcb, u16* __restrict__ dstb, int ntot) {
    int i = blockIdx.x * 256 + threadIdx.x;  // 4 elems per thread
    if (i >= ntot * 64) return;
    const float4* s = (const float4*)(blockIdx.y ? dst : src);
    u16* o = blockIdx.y ? dstb : srcb;
    float4 v = s[i];
    ushort4 u = {f2bf(v.x), f2bf(v.y), f2bf(v.z), f2bf(v.w)};
    ((ushort4*)o)[i] = u;
}

// Generic bf16 MFMA GEMM: C[m][n] = sum_k Arow[m][k] * Bw[n][k].
// A is split: k<K1 from A (lda), k>=K1 from A2 (lda2, col k-K1).
// Epilogue: v = acc*scale[n]+shift[n]; relu(flag1); +resid[m*256+n]; store
// (flag2: f32 out else bf16).
__global__ __launch_bounds__(256) void k_gemm(
    const u16* __restrict__ A, int lda,
    const u16* __restrict__ A2, int lda2, int K1,
    const u16* __restrict__ Bw, int K,
    const float* __restrict__ scale, const float* __restrict__ shift,
    const float* __restrict__ resid,
    void* __restrict__ Cout, int ldc, int flags) {
    __shared__ u16 Al[128 * 32];
    __shared__ u16 Bl[128 * 32];
    int m0 = blockIdx.x * 128, n0 = blockIdx.y * 128;
    int tid = threadIdx.x;
    int w = tid >> 6, lane = tid & 63;
    int wm = w & 1, wn = w >> 1;
    int l15 = lane & 15, quad = lane >> 4;
    f4v acc[4][4] = {};

    for (int k0 = 0; k0 < K; k0 += 32) {
        const u16* Asrc; int aL, acol;
        if (k0 < K1) { Asrc = A; aL = lda; acol = k0; }
        else { Asrc = A2; aL = lda2; acol = k0 - K1; }
#pragma unroll
        for (int c = tid; c < 512; c += 256) {  // 2 iters: 16B chunks
            int row = c >> 2, off = (c & 3) << 3;
            *(uint4*)(&Al[row * 32 + off]) =
                *(const uint4*)(&Asrc[(size_t)(m0 + row) * aL + acol + off]);
            *(uint4*)(&Bl[row * 32 + off]) =
                *(const uint4*)(&Bw[(size_t)(n0 + row) * K + k0 + off]);
        }
        __syncthreads();
        s8v af[4], bf[4];
#pragma unroll
        for (int i = 0; i < 4; i++)
            af[i] = *(const s8v*)(&Al[(wm * 64 + i * 16 + l15) * 32 + quad * 8]);
#pragma unroll
        for (int j = 0; j < 4; j++)
            bf[j] = *(const s8v*)(&Bl[(wn * 64 + j * 16 + l15) * 32 + quad * 8]);
#pragma unroll
        for (int i = 0; i < 4; i++)
#pragma unroll
            for (int j = 0; j < 4; j++)
                acc[i][j] = __builtin_amdgcn_mfma_f32_16x16x32_bf16(
                    af[i], bf[j], acc[i][j], 0, 0, 0);
        __syncthreads();
    }
#pragma unroll
    for (int i = 0; i < 4; i++) {
#pragma unroll
        for (int j = 0; j < 4; j++) {
            int n = n0 + wn * 64 + j * 16 + l15;
            float sc = scale ? scale[n] : 1.f;
            float sh = shift ? shift[n] : 0.f;
#pragma unroll
            for (int r = 0; r < 4; r++) {
                int m = m0 + wm * 64 + i * 16 + quad * 4 + r;
                float v = acc[i][j][r] * sc + sh;
                if (flags & 1) v = fmaxf(v, 0.f);
                if (resid) v += resid[(size_t)m * 256 + n];
                if (flags & 2) ((float*)Cout)[(size_t)m * ldc + n] = v;
                else ((u16*)Cout)[(size_t)m * ldc + n] = f2bf(v);
            }
        }
    }
}

// Attention v2: block (b, h, z); z splits q-strips. 4 waves, wave = 16 q-rows
// per strip, strips step by 256 rows. K read direct from global (no reuse
// within a strip). LDS: V^T [32][520] + per-wave P chunk [16][136] = 49.5 KB
// -> 2 blocks/CU. Full-row scores live in 128 VGPRs; P column-chunked (128)
// through per-wave LDS (no barriers in strip loop).
__global__ __launch_bounds__(256) void k_attn(
    const u16* __restrict__ qb, const u16* __restrict__ kvb,
    const int* __restrict__ meta, u16* __restrict__ msgb) {
    __shared__ u16 Vl[32 * VSTR];
    __shared__ u16 Pl[4 * 16 * PSTR];
    int b = blockIdx.x, h = blockIdx.y, z = blockIdx.z;
    int ns = meta[b], nd = meta[64 + b];
    int soff = meta[128 + b], doff = meta[192 + b];
    int tid = threadIdx.x, w = tid >> 6, lane = tid & 63;
    int l15 = lane & 15, quad = lane >> 4;

    // stage V^T (zero tail cols m>=ns)
    for (int m = tid; m < 512; m += 256) {
        if (m < ns) {
            uint4 vv[4];
            const uint4* vsrc =
                (const uint4*)&kvb[(size_t)(soff + m) * 256 + 128 + h * 32];
#pragma unroll
            for (int q4 = 0; q4 < 4; q4++) vv[q4] = vsrc[q4];
            const u16* pv = (const u16*)vv;
#pragma unroll
            for (int d = 0; d < 32; d++) Vl[d * VSTR + m] = pv[d];
        } else {
#pragma unroll
            for (int d = 0; d < 32; d++) Vl[d * VSTR + m] = 0;
        }
    }
    __syncthreads();

    u16* Pw = Pl + w * 16 * PSTR;
    const float qscale = 0.17677669529663687f;  // 1/sqrt(32)
    int nt = (ns + 15) >> 4;                    // live 16-col K tiles

    for (int s0 = z * 64 + w * 16; s0 < nd; s0 += 256) {
        int qr = min(s0 + l15, nd - 1);
        s8v aq = *(const s8v*)&qb[(size_t)(doff + qr) * 128 + h * 32 + quad * 8];

        f4v scv[32];
#pragma unroll
        for (int t = 0; t < 32; t++) {
            if (t < nt) {
                int kr = min(t * 16 + l15, ns - 1);
                s8v bk_ = *(const s8v*)&kvb[(size_t)(soff + kr) * 256 + h * 32 + quad * 8];
                scv[t] = __builtin_amdgcn_mfma_f32_16x16x32_bf16(
                    aq, bk_, (f4v){0.f, 0.f, 0.f, 0.f}, 0, 0, 0);
            } else {
                scv[t] = (f4v){0.f, 0.f, 0.f, 0.f};
            }
        }
        float mrow[4] = {-1e30f, -1e30f, -1e30f, -1e30f};
#pragma unroll
        for (int t = 0; t < 32; t++) {
            bool ok = (t * 16 + l15) < ns;
#pragma unroll
            for (int r = 0; r < 4; r++) {
                float v = ok ? scv[t][r] * qscale : -1e30f;
                scv[t][r] = v;
                mrow[r] = fmaxf(mrow[r], v);
            }
        }
#pragma unroll
        for (int r = 0; r < 4; r++) {
            float m_ = mrow[r];
#pragma unroll
            for (int x = 1; x < 16; x <<= 1) m_ = fmaxf(m_, __shfl_xor(m_, x, 16));
            mrow[r] = m_;
        }
        float lsum[4] = {0.f, 0.f, 0.f, 0.f};
#pragma unroll
        for (int t = 0; t < 32; t++)
#pragma unroll
            for (int r = 0; r < 4; r++) {
                float e = __expf(scv[t][r] - mrow[r]);
                scv[t][r] = e;
                lsum[r] += e;
            }
        float inv[4];
#pragma unroll
        for (int r = 0; r < 4; r++) {
            float s_ = lsum[r];
#pragma unroll
            for (int x = 1; x < 16; x <<= 1) s_ += __shfl_xor(s_, x, 16);
            inv[r] = 1.f / s_;
        }

        f4v oa[2] = {{0.f, 0.f, 0.f, 0.f}, {0.f, 0.f, 0.f, 0.f}};
#pragma unroll
        for (int c = 0; c < 4; c++) {  // 128-col P chunks
#pragma unroll
            for (int tt = 0; tt < 8; tt++) {
                int t = c * 8 + tt;
#pragma unroll
                for (int r = 0; r < 4; r++)
                    Pw[(quad * 4 + r) * PSTR + tt * 16 + l15] = f2bf(scv[t][r]);
            }
            // same-wave ds RAW: compiler inserts lgkmcnt; per-wave buffer
#pragma unroll
            for (int kc = 0; kc < 4; kc++) {
                s8v ap = *(const s8v*)&Pw[l15 * PSTR + kc * 32 + quad * 8];
#pragma unroll
                for (int t2 = 0; t2 < 2; t2++) {
                    s8v bv_ = *(const s8v*)&Vl[(t2 * 16 + l15) * VSTR
                                               + c * 128 + kc * 32 + quad * 8];
                    oa[t2] = __builtin_amdgcn_mfma_f32_16x16x32_bf16(
                        ap, bv_, oa[t2], 0, 0, 0);
                }
            }
        }
#pragma unroll
        for (int t2 = 0; t2 < 2; t2++)
#pragma unroll
            for (int r = 0; r < 4; r++) {
                int row = s0 + quad * 4 + r;
                if (row < nd)
                    msgb[(size_t)(doff + row) * 128 + h * 32 + t2 * 16 + l15] =
                        f2bf(oa[t2][r] * inv[r]);
            }
    }
}

extern "C" void kernel_launch(void* const* d_in, const int* in_sizes, int n_in,
                              void* d_out, int out_size, void* d_ws, size_t ws_size,
                              hipStream_t stream) {
    const float* src_h = (const float*)d_in[0];
    const float* dst_h = (const float*)d_in[1];
    const int* snv = (const int*)d_in[2];
    const int* dnv = (const int*)d_in[3];
    const float* Wq = (const float*)d_in[4];  const float* bq = (const float*)d_in[5];
    const float* Wk = (const float*)d_in[6];  const float* bk = (const float*)d_in[7];
    const float* Wv = (const float*)d_in[8];  const float* bv = (const float*)d_in[9];
    const float* Wm = (const float*)d_in[10]; const float* bm = (const float*)d_in[11];
    const float* W1 = (const float*)d_in[12]; const float* b1 = (const float*)d_in[13];
    const float* g1 = (const float*)d_in[14]; const float* be1 = (const float*)d_in[15];
    const float* rm1 = (const float*)d_in[16]; const float* rv1 = (const float*)d_in[17];
    const float* W2 = (const float*)d_in[18]; const float* b2 = (const float*)d_in[19];
    const float* g2 = (const float*)d_in[20]; const float* be2 = (const float*)d_in[21];
    const float* rm2 = (const float*)d_in[22]; const float* rv2 = (const float*)d_in[23];

    int ntot = out_size / HDIM;  // 24576
    int mt = ntot / 128;         // 192 M-tiles

    // ws layout (~31 MB):
    char* ws = (char*)d_ws;
    int* meta = (int*)ws;                       // @0
    float* bqp = (float*)(ws + 4096);
    float* bkvp = (float*)(ws + 4608);
    float* bmp = (float*)(ws + 5632);
    float* sc1 = (float*)(ws + 6144);
    float* sh1 = (float*)(ws + 7168);
    float* sc2 = (float*)(ws + 8192);
    float* sh2 = (float*)(ws + 9216);
    u16* pWq = (u16*)(ws + 16384);              // 32768 elems
    u16* pWkv = (u16*)(ws + 81920);             // 65536
    u16* pWm = (u16*)(ws + 212992);             // 16384
    u16* pW1 = (u16*)(ws + 245760);             // 98304
    u16* pW2 = (u16*)(ws + 442368);             // 65536
    u16* srcb = (u16*)(ws + 1048576);           // ntot*256 bf16 (12.6 MB)
    u16* x1b = srcb;                            // reuse after G_kv consumed
    u16* dstb = (u16*)(ws + 13631488);          // ntot*256 bf16 (12.6 MB)
    u16* hm = (u16*)(ws + 26214400);            // ntot*128 bf16 (6.3 MB)

    // d_out doubles as q/kv/msg scratch (exactly out_size*4 bytes):
    u16* qb = (u16*)d_out;                      // ntot*128
    u16* kvb = qb + (size_t)ntot * 128;         // ntot*256
    u16* msgb = kvb + (size_t)ntot * 256;       // ntot*128

    k_prep<<<dim3(1093), dim3(256), 0, stream>>>(
        Wq, bq, Wk, bk, Wv, bv, Wm, bm, W1, b1, g1, be1, rm1, rv1,
        W2, b2, g2, be2, rm2, rv2, snv, dnv, meta,
        pWq, pWkv, pWm, pW1, pW2, bqp, bkvp, bmp, sc1, sh1, sc2, sh2);
    k_convert<<<dim3(ntot * 64 / 256, 2), dim3(256), 0, stream>>>(
        src_h, dst_h, srcb, dstb, ntot);
    // q = dstb @ Wq'^T + bq'
    k_gemm<<<dim3(mt, 1), dim3(256), 0, stream>>>(
        dstb, 256, dstb, 256, 256, pWq, 256, nullptr, bqp, nullptr, qb, 128, 0);
    // k|v = srcb @ Wkv'^T + bkv'
    k_gemm<<<dim3(mt, 2), dim3(256), 0, stream>>>(
        srcb, 256, srcb, 256, 256, pWkv, 256, nullptr, bkvp, nullptr, kvb, 256, 0);
    k_attn<<<dim3(B_SEG, NHEADS, 4), dim3(256), 0, stream>>>(qb, kvb, meta, msgb);
    // hm = msg @ Wm'^T + bm
    k_gemm<<<dim3(mt, 1), dim3(256), 0, stream>>>(
        msgb, 128, msgb, 128, 128, pWm, 128, nullptr, bmp, nullptr, hm, 128, 0);
    // x1 = relu(bn1([dstb|hm] @ W1^T))
    k_gemm<<<dim3(mt, 2), dim3(256), 0, stream>>>(
        dstb, 256, hm, 128, 256, pW1, 384, sc1, sh1, nullptr, x1b, 256, 1);
    // out = dst_h + bn2(x1 @ W2^T)   (f32, overwrites scratch in d_out)
    k_gemm<<<dim3(mt, 2), dim3(256), 0, stream>>>(
        x1b, 256, x1b, 256, 256, pW2, 256, sc2, sh2, dst_h, d_out, 256, 2);
}

// Round 6
// 235.552 us; speedup vs baseline: 1.3688x; 1.3688x over previous
//
#include <hip/hip_runtime.h>
#include <hip/hip_bf16.h>
#include <math.h>

#define B_SEG 64
#define HDIM 256
#define HDIV 128
#define NHEADS 4
#define DH 32
#define KSTR 40    // K LDS row stride (elems, 80 B: 16B-aligned)
#define VSTR 520   // V^T row stride (1040 B: 16B-aligned)
#define PSTR 136   // P row stride (272 B: 16B-aligned)
#define QSC 0.17677669529663687f

typedef unsigned short u16;
typedef unsigned int u32;

typedef __attribute__((ext_vector_type(8))) short s8v;   // 8 x bf16
typedef __attribute__((ext_vector_type(4))) float f4v;   // mfma accum

__device__ __forceinline__ u16 f2bf(float f) {
    u32 v;
    __builtin_memcpy(&v, &f, 4);
    u32 r = v + 0x7fffu + ((v >> 16) & 1u);
    return (u16)(r >> 16);
}

// async global->LDS, 16B per lane. LDS dest = wave-uniform base + lane*16.
__device__ __forceinline__ void async_cp16(const u16* g, u16* l) {
    __builtin_amdgcn_global_load_lds(
        (const __attribute__((address_space(1))) u32*)g,
        (__attribute__((address_space(3))) u32*)l, 16, 0, 0);
}

// ============ prep: weights (bf16 + head-deinterleave + Wm-folding), meta,
// ============ activation f32->bf16 convert — one launch.
// head permute: dest channel c' = h*32+d <-> src c = d*4+h.
// pW1f = [W1[:,0:256] | W1[:,256:384] @ Wm'] (256 x 384); b1 absorbs W1b@bm.
__global__ __launch_bounds__(256) void k_prep(
    const float* __restrict__ Wq, const float* __restrict__ bq,
    const float* __restrict__ Wk, const float* __restrict__ bk,
    const float* __restrict__ Wv, const float* __restrict__ bv,
    const float* __restrict__ Wm, const float* __restrict__ bm,
    const float* __restrict__ W1, const float* __restrict__ b1,
    const float* __restrict__ g1, const float* __restrict__ be1,
    const float* __restrict__ rm1, const float* __restrict__ rv1,
    const float* __restrict__ W2, const float* __restrict__ b2,
    const float* __restrict__ g2, const float* __restrict__ be2,
    const float* __restrict__ rm2, const float* __restrict__ rv2,
    const int* __restrict__ sc_raw, const int* __restrict__ dc_raw,
    const float* __restrict__ src_h, const float* __restrict__ dst_h,
    int* __restrict__ meta,
    u16* __restrict__ pWq, u16* __restrict__ pWkv,
    u16* __restrict__ pW1f, u16* __restrict__ pW2,
    float* __restrict__ bqp, float* __restrict__ bkvp,
    float* __restrict__ sc1, float* __restrict__ sh1,
    float* __restrict__ sc2, float* __restrict__ sh2,
    u16* __restrict__ srcb, u16* __restrict__ dstb, int ntot) {
    if (blockIdx.x < 1028) {
        int idx = blockIdx.x * 256 + threadIdx.x;
        if (idx < 32768) {                       // Wq' rows permuted
            int cp = idx >> 8, k = idx & 255;
            int c = ((cp & 31) << 2) | (cp >> 5);
            pWq[idx] = f2bf(Wq[c * 256 + k]);
        } else if (idx < 98304) {                // Wkv': k rows 0..127, v 128..255
            int i = idx - 32768;
            int rp = i >> 8, k = i & 255;
            int r = rp & 127;
            int c = ((r & 31) << 2) | (r >> 5);
            float v = (rp < 128) ? Wk[c * 256 + k] : Wv[c * 256 + k];
            pWkv[i] = f2bf(v);
        } else if (idx < 163840) {               // W1 cols 0..255 plain
            int i = idx - 98304;
            int o = i >> 8, k = i & 255;
            pW1f[o * 384 + k] = f2bf(W1[o * 384 + k]);
        } else if (idx < 196608) {               // W1bm = W1b @ Wm' (cols 256..383)
            int i = idx - 163840;
            int o = i >> 7, cp = i & 127;
            int c = ((cp & 31) << 2) | (cp >> 5);
            float acc = 0.f;
            for (int j = 0; j < 128; j++)
                acc += W1[o * 384 + 256 + j] * Wm[j * 128 + c];
            pW1f[o * 384 + 256 + cp] = f2bf(acc);
        } else if (idx < 262144) {               // W2 plain
            int i = idx - 196608;
            pW2[i] = f2bf(W2[i]);
        } else if (idx < 263168) {               // params
            int p = idx - 262144;
            if (p < 128) {
                int c = ((p & 31) << 2) | (p >> 5);
                bqp[p] = bq[c] * QSC;            // 1/sqrt(dh) folded into q
            } else if (p < 384) {
                int r = p - 128; int rr = r & 127;
                int c = ((rr & 31) << 2) | (rr >> 5);
                bkvp[r] = (r < 128) ? bk[c] : bv[c];
            } else if (p < 640) {
                int o = p - 384;
                float bsum = 0.f;                // fold W1b @ bm into b1
                for (int j = 0; j < 128; j++)
                    bsum += W1[o * 384 + 256 + j] * bm[j];
                float s = g1[o] * rsqrtf(rv1[o] + 1e-5f);
                sc1[o] = s;
                sh1[o] = (b1[o] + bsum - rm1[o]) * s + be1[o];
            } else if (p < 896) {
                int o = p - 640;
                float s = g2[o] * rsqrtf(rv2[o] + 1e-5f);
                sc2[o] = s;
                sh2[o] = (b2[o] - rm2[o]) * s + be2[o];
            }
        }
    } else if (blockIdx.x == 1028) {             // ragged meta
        if (threadIdx.x == 0) {
            bool is64 = (sc_raw[1] == 0);        // counts in [256,512]
            int so = 0, dofs = 0;
            for (int i = 0; i < B_SEG; i++) {
                int s = is64 ? sc_raw[2 * i] : sc_raw[i];
                int d = is64 ? dc_raw[2 * i] : dc_raw[i];
                meta[i] = s; meta[64 + i] = d;
                meta[128 + i] = so; meta[192 + i] = dofs;
                so += s; dofs += d;
            }
        }
    } else {                                     // f32->bf16 convert (both acts)
        int i = (blockIdx.x - 1029) * 256 + threadIdx.x;
        int half = ntot * 64;
        const float4* s;
        u16* o;
        int j = i;
        if (i < half) { s = (const float4*)src_h; o = srcb; }
        else { s = (const float4*)dst_h; o = dstb; j = i - half; }
        float4 v = s[j];
        ushort4 u = {f2bf(v.x), f2bf(v.y), f2bf(v.z), f2bf(v.w)};
        ((ushort4*)o)[j] = u;
    }
}

// ============ generic 128x128 MFMA GEMM body, async LDS staging ============
// C[m][n] = sum_k Arow[m][k]*Bw[n][k]; A split at K1 -> A2. Epilogue:
// v = acc*(flags&4?QSC:1)*scale[n] + shift[n]; relu(1); +resid[m*256+n];
// store f32(2) else bf16.
__device__ __forceinline__ void gemm_body(
    const u16* __restrict__ A, int lda,
    const u16* __restrict__ A2, int lda2, int K1,
    const u16* __restrict__ Bw, int K, int m0, int n0,
    const float* __restrict__ scale, const float* __restrict__ shift,
    const float* __restrict__ resid,
    void* __restrict__ Cout, int ldc, int flags,
    u16* Al, u16* Bl) {
    int tid = threadIdx.x;
    int w = tid >> 6, lane = tid & 63;
    int wm = w & 1, wn = w >> 1;
    int l15 = lane & 15, quad = lane >> 4;
    int srow = w * 32 + (lane >> 2);        // staging row (this call)
    int scol = (lane & 3) << 3;             // staging col (elems)
    u16* al0 = Al + w * 1024;               // wave-uniform LDS bases
    u16* bl0 = Bl + w * 1024;
    f4v acc[4][4] = {};

    for (int k0 = 0; k0 < K; k0 += 32) {
        const u16* Ag; int aL, acol;
        if (k0 < K1) { Ag = A; aL = lda; acol = k0; }
        else { Ag = A2; aL = lda2; acol = k0 - K1; }
        async_cp16(&Ag[(size_t)(m0 + srow) * aL + acol + scol], al0);
        async_cp16(&Ag[(size_t)(m0 + srow + 16) * aL + acol + scol], al0 + 512);
        async_cp16(&Bw[(size_t)(n0 + srow) * K + k0 + scol], bl0);
        async_cp16(&Bw[(size_t)(n0 + srow + 16) * K + k0 + scol], bl0 + 512);
        __syncthreads();
        s8v af[4], bf[4];
#pragma unroll
        for (int i = 0; i < 4; i++)
            af[i] = *(const s8v*)(&Al[(wm * 64 + i * 16 + l15) * 32 + quad * 8]);
#pragma unroll
        for (int j = 0; j < 4; j++)
            bf[j] = *(const s8v*)(&Bl[(wn * 64 + j * 16 + l15) * 32 + quad * 8]);
#pragma unroll
        for (int i = 0; i < 4; i++)
#pragma unroll
            for (int j = 0; j < 4; j++)
                acc[i][j] = __builtin_amdgcn_mfma_f32_16x16x32_bf16(
                    af[i], bf[j], acc[i][j], 0, 0, 0);
        __syncthreads();
    }
#pragma unroll
    for (int i = 0; i < 4; i++) {
#pragma unroll
        for (int j = 0; j < 4; j++) {
            int n = n0 + wn * 64 + j * 16 + l15;
            float sc = scale ? scale[n] : 1.f;
            float sh = shift ? shift[n] : 0.f;
#pragma unroll
            for (int r = 0; r < 4; r++) {
                int m = m0 + wm * 64 + i * 16 + quad * 4 + r;
                float v = acc[i][j][r];
                if (flags & 4) v *= QSC;
                v = v * sc + sh;
                if (flags & 1) v = fmaxf(v, 0.f);
                if (resid) v += resid[(size_t)m * 256 + n];
                if (flags & 2) ((float*)Cout)[(size_t)m * ldc + n] = v;
                else ((u16*)Cout)[(size_t)m * ldc + n] = f2bf(v);
            }
        }
    }
}

// fused q + k|v projections: y==0 -> q (with QSC fold), y==1,2 -> kv halves
__global__ __launch_bounds__(256) void k_qkv(
    const u16* __restrict__ dstb, const u16* __restrict__ srcb,
    const u16* __restrict__ pWq, const u16* __restrict__ pWkv,
    const float* __restrict__ bqp, const float* __restrict__ bkvp,
    u16* __restrict__ qb, u16* __restrict__ kvb) {
    __shared__ u16 Al[4096];
    __shared__ u16 Bl[4096];
    int m0 = blockIdx.x * 128;
    if (blockIdx.y == 0)
        gemm_body(dstb, 256, dstb, 256, 256, pWq, 256, m0, 0,
                  nullptr, bqp, nullptr, qb, 128, 4, Al, Bl);
    else
        gemm_body(srcb, 256, srcb, 256, 256, pWkv, 256, m0, (blockIdx.y - 1) * 128,
                  nullptr, bkvp, nullptr, kvb, 256, 0, Al, Bl);
}

__global__ __launch_bounds__(256) void k_gemm(
    const u16* __restrict__ A, int lda,
    const u16* __restrict__ A2, int lda2, int K1,
    const u16* __restrict__ Bw, int K,
    const float* __restrict__ scale, const float* __restrict__ shift,
    const float* __restrict__ resid,
    void* __restrict__ Cout, int ldc, int flags) {
    __shared__ u16 Al[4096];
    __shared__ u16 Bl[4096];
    gemm_body(A, lda, A2, lda2, K1, Bw, K, blockIdx.x * 128, blockIdx.y * 128,
              scale, shift, resid, Cout, ldc, flags, Al, Bl);
}

// ============ attention v3: block (b,h), 512 threads (8 waves) ============
// K [512][40] + V^T [32][520] + per-wave P [16][136] in 107 KB dynamic LDS,
// staged once; strip loop barrier-free. No max-subtraction (scores bounded,
// 1/sqrt(dh) pre-folded into q). Dead K-tiles/chunks skipped via nt/nc.
__global__ __launch_bounds__(512, 2) void k_attn(
    const u16* __restrict__ qb, const u16* __restrict__ kvb,
    const int* __restrict__ meta, u16* __restrict__ msgb) {
    extern __shared__ u16 sm[];
    u16* Kl = sm;                       // 512*40  = 40960 B
    u16* Vl = sm + 512 * KSTR;          // 32*520  = 33280 B
    u16* Pl = Vl + 32 * VSTR;           // 8*16*136= 34816 B
    int b = blockIdx.x, h = blockIdx.y;
    int ns = meta[b], nd = meta[64 + b];
    int soff = meta[128 + b], doff = meta[192 + b];
    int tid = threadIdx.x, w = tid >> 6, lane = tid & 63;
    int l15 = lane & 15, quad = lane >> 4;

    {   // stage K rows + V^T cols: one row per thread
        int m = tid;
        if (m < ns) {
            const uint4* ks = (const uint4*)&kvb[(size_t)(soff + m) * 256 + h * 32];
#pragma unroll
            for (int q4 = 0; q4 < 4; q4++)
                *(uint4*)&Kl[m * KSTR + q4 * 8] = ks[q4];
            uint4 vv[4];
            const uint4* vs = (const uint4*)&kvb[(size_t)(soff + m) * 256 + 128 + h * 32];
#pragma unroll
            for (int q4 = 0; q4 < 4; q4++) vv[q4] = vs[q4];
            const u16* pv = (const u16*)vv;
#pragma unroll
            for (int d = 0; d < 32; d++) Vl[d * VSTR + m] = pv[d];
        } else {  // zero V tail (P=0 there; avoid 0*NaN). K tail garbage is masked.
#pragma unroll
            for (int d = 0; d < 32; d++) Vl[d * VSTR + m] = 0;
        }
    }
    __syncthreads();

    int nt = (ns + 15) >> 4;    // live 16-col K tiles
    int nc = (ns + 127) >> 7;   // live 128-col P chunks
    u16* Pw = Pl + w * 16 * PSTR;

    for (int s0 = w * 16; s0 < nd; s0 += 128) {   // 8 waves x 16 rows
        int qr = min(s0 + l15, nd - 1);
        s8v aq = *(const s8v*)&qb[(size_t)(doff + qr) * 128 + h * 32 + quad * 8];

        f4v e[32];
        float lsum[4] = {0.f, 0.f, 0.f, 0.f};
#pragma unroll
        for (int t = 0; t < 32; t++) {
            if (t < nt) {
                int kr = t * 16 + l15;
                s8v bk = *(const s8v*)&Kl[kr * KSTR + quad * 8];
                f4v s_ = __builtin_amdgcn_mfma_f32_16x16x32_bf16(
                    aq, bk, (f4v){0.f, 0.f, 0.f, 0.f}, 0, 0, 0);
                bool ok = kr < ns;
#pragma unroll
                for (int r = 0; r < 4; r++) {
                    float ev = ok ? __expf(s_[r]) : 0.f;
                    e[t][r] = ev;
                    lsum[r] += ev;
                }
            } else {
#pragma unroll
                for (int r = 0; r < 4; r++) e[t][r] = 0.f;
            }
        }
        float inv[4];
#pragma unroll
        for (int r = 0; r < 4; r++) {
            float s_ = lsum[r];
#pragma unroll
            for (int x = 1; x < 16; x <<= 1) s_ += __shfl_xor(s_, x, 16);
            inv[r] = 1.f / s_;
        }

        f4v oa0 = {0.f, 0.f, 0.f, 0.f}, oa1 = {0.f, 0.f, 0.f, 0.f};
#pragma unroll
        for (int c = 0; c < 4; c++) {             // compile-time c (VGPR array idx)
            if (c < nc) {
#pragma unroll
                for (int tt = 0; tt < 8; tt++)
#pragma unroll
                    for (int r = 0; r < 4; r++)
                        Pw[(quad * 4 + r) * PSTR + tt * 16 + l15] =
                            f2bf(e[c * 8 + tt][r]);
#pragma unroll
                for (int kc = 0; kc < 4; kc++) {
                    s8v ap = *(const s8v*)&Pw[l15 * PSTR + kc * 32 + quad * 8];
                    s8v bv0 = *(const s8v*)&Vl[l15 * VSTR + c * 128 + kc * 32 + quad * 8];
                    s8v bv1 = *(const s8v*)&Vl[(16 + l15) * VSTR + c * 128 + kc * 32 + quad * 8];
                    oa0 = __builtin_amdgcn_mfma_f32_16x16x32_bf16(ap, bv0, oa0, 0, 0, 0);
                    oa1 = __builtin_amdgcn_mfma_f32_16x16x32_bf16(ap, bv1, oa1, 0, 0, 0);
                }
            }
        }
#pragma unroll
        for (int r = 0; r < 4; r++) {
            int row = s0 + quad * 4 + r;
            if (row < nd) {
                size_t base = (size_t)(doff + row) * 128 + h * 32;
                msgb[base + l15] = f2bf(oa0[r] * inv[r]);
                msgb[base + 16 + l15] = f2bf(oa1[r] * inv[r]);
            }
        }
    }
}

extern "C" void kernel_launch(void* const* d_in, const int* in_sizes, int n_in,
                              void* d_out, int out_size, void* d_ws, size_t ws_size,
                              hipStream_t stream) {
    const float* src_h = (const float*)d_in[0];
    const float* dst_h = (const float*)d_in[1];
    const int* snv = (const int*)d_in[2];
    const int* dnv = (const int*)d_in[3];
    const float* Wq = (const float*)d_in[4];  const float* bq = (const float*)d_in[5];
    const float* Wk = (const float*)d_in[6];  const float* bk = (const float*)d_in[7];
    const float* Wv = (const float*)d_in[8];  const float* bv = (const float*)d_in[9];
    const float* Wm = (const float*)d_in[10]; const float* bm = (const float*)d_in[11];
    const float* W1 = (const float*)d_in[12]; const float* b1 = (const float*)d_in[13];
    const float* g1 = (const float*)d_in[14]; const float* be1 = (const float*)d_in[15];
    const float* rm1 = (const float*)d_in[16]; const float* rv1 = (const float*)d_in[17];
    const float* W2 = (const float*)d_in[18]; const float* b2 = (const float*)d_in[19];
    const float* g2 = (const float*)d_in[20]; const float* be2 = (const float*)d_in[21];
    const float* rm2 = (const float*)d_in[22]; const float* rv2 = (const float*)d_in[23];

    int ntot = out_size / HDIM;  // 24576
    int mt = ntot / 128;         // 192

    // ws layout (~26.2 MB):
    char* ws = (char*)d_ws;
    int* meta = (int*)ws;
    float* bqp = (float*)(ws + 4096);           // 128
    float* bkvp = (float*)(ws + 4608);          // 256
    float* sc1 = (float*)(ws + 6144);           // 256
    float* sh1 = (float*)(ws + 7168);           // 256
    float* sc2 = (float*)(ws + 8192);           // 256
    float* sh2 = (float*)(ws + 9216);           // 256
    u16* pWq = (u16*)(ws + 16384);              // 32768 elems
    u16* pWkv = (u16*)(ws + 81920);             // 65536
    u16* pW1f = (u16*)(ws + 212992);            // 98304 (256x384)
    u16* pW2 = (u16*)(ws + 409600);             // 65536
    u16* srcb = (u16*)(ws + 1048576);           // ntot*256 bf16 (12.6 MB)
    u16* x1b = srcb;                            // reuse after k_qkv consumed
    u16* dstb = (u16*)(ws + 13631488);          // ntot*256 bf16 (12.6 MB)

    // d_out doubles as q/kv/msg scratch (exactly out_size*4 bytes):
    u16* qb = (u16*)d_out;                      // ntot*128
    u16* kvb = qb + (size_t)ntot * 128;         // ntot*256
    u16* msgb = kvb + (size_t)ntot * 256;       // ntot*128

    hipFuncSetAttribute((const void*)k_attn,
                        hipFuncAttributeMaxDynamicSharedMemorySize, 131072);

    // 1) weights + meta + activation convert
    k_prep<<<dim3(1029 + ntot / 2), dim3(256), 0, stream>>>(
        Wq, bq, Wk, bk, Wv, bv, Wm, bm, W1, b1, g1, be1, rm1, rv1,
        W2, b2, g2, be2, rm2, rv2, snv, dnv, src_h, dst_h, meta,
        pWq, pWkv, pW1f, pW2, bqp, bkvp, sc1, sh1, sc2, sh2,
        srcb, dstb, ntot);
    // 2) q (QSC-folded) + k|v projections
    k_qkv<<<dim3(mt, 3), dim3(256), 0, stream>>>(
        dstb, srcb, pWq, pWkv, bqp, bkvp, qb, kvb);
    // 3) attention
    k_attn<<<dim3(B_SEG, NHEADS), dim3(512), 109056, stream>>>(qb, kvb, meta, msgb);
    // 4) x1 = relu(bn1([dstb | msgb] @ pW1f^T))   (Wm folded into pW1f)
    k_gemm<<<dim3(mt, 2), dim3(256), 0, stream>>>(
        dstb, 256, msgb, 128, 256, pW1f, 384, sc1, sh1, nullptr, x1b, 256, 1);
    // 5) out = dst_h + bn2(x1 @ pW2^T)  (f32, overwrites scratch in d_out)
    k_gemm<<<dim3(mt, 2), dim3(256), 0, stream>>>(
        x1b, 256, x1b, 256, 256, pW2, 256, sc2, sh2, dst_h, d_out, 256, 2);
}